// Round 1
// 1235.734 us; speedup vs baseline: 1.1361x; 1.1361x over previous
//
#include <hip/hip_runtime.h>
#include <stdint.h>

#define OUTF 11008
#define INF  4096
#define NG   32      // groups = INF/128
#define TOK  8192
#define KB4  2048    // int32 per qweight row = INF/2

// ---- main GEMM geometry: 256x256 tile, 8 waves, 8-phase counted-vmcnt ----
#define BM 256
#define BN 256
#define BK 64
#define NT (INF / BK)    // 64 K-tiles
#define GX (OUTF / BN)   // 43
#define GY (TOK / BM)    // 32
#define NWG (GX * GY)    // 1376, % 8 == 0 -> simple bijective XCD swizzle

typedef unsigned short u16;
typedef __attribute__((ext_vector_type(8))) short bf16x8;
typedef __attribute__((ext_vector_type(4))) float f32x4;

// fp32 -> bf16 round-to-nearest-even (inputs finite)
__device__ inline u16 f2bf(float f) {
  union { float f; uint32_t u; } v; v.f = f;
  return (u16)((v.u + 0x7fff + ((v.u >> 16) & 1)) >> 16);
}

// async global->LDS, 16B per lane; lds dest must be wave-uniform base (+lane*16 implicit)
__device__ inline void async_copy16(const void* g, const void* l) {
  __builtin_amdgcn_global_load_lds(
      (__attribute__((address_space(1))) void*)(g),
      (__attribute__((address_space(3))) void*)(l), 16, 0, 0);
}

#define FENCE() asm volatile("" ::: "memory")
#define BAR()   do { FENCE(); __builtin_amdgcn_s_barrier(); FENCE(); } while (0)
#define VMCNT(n) asm volatile("s_waitcnt vmcnt(" #n ")" ::: "memory")

// ---------------- preprocessing kernels (unchanged) ----------------

__global__ void dequant_w(const int* __restrict__ QW, const float* __restrict__ scales,
                          const float* __restrict__ zeros, u16* __restrict__ Wb) {
  const int idx = blockIdx.x * 256 + threadIdx.x;   // one per 8 packed ints
  const int e = idx * 8;
  const int o = e >> 11;            // /KB4
  const int c = e & (KB4 - 1);      // multiple of 8 -> both int4s in same group
  const int g = c >> 6;
  const float s = scales[o * NG + g];
  const float z = zeros[o * NG + g];
  const float zs = -z * s;
#pragma unroll
  for (int h = 0; h < 2; ++h) {
    const int4 q = *(const int4*)(QW + (size_t)o * KB4 + c + h * 4);
    const int qq[4] = {q.x, q.y, q.z, q.w};
    union { u16 t[8]; int4 v; } u;
#pragma unroll
    for (int j = 0; j < 4; ++j) {
      u.t[2 * j]     = f2bf(fmaf((float)(qq[j] & 15), s, zs));
      u.t[2 * j + 1] = f2bf(fmaf((float)((qq[j] >> 4) & 15), s, zs));
    }
    *(int4*)(Wb + (size_t)o * INF + 2 * (c + h * 4)) = u.v;
  }
}

__global__ void cvt_x(const float* __restrict__ X, u16* __restrict__ Xb) {
  const size_t base = ((size_t)blockIdx.x * 256 + threadIdx.x) * 16;
#pragma unroll
  for (int h = 0; h < 2; ++h) {
    const float4 a = *(const float4*)(X + base + h * 8);
    const float4 b = *(const float4*)(X + base + h * 8 + 4);
    union { u16 t[8]; int4 v; } u;
    u.t[0] = f2bf(a.x); u.t[1] = f2bf(a.y); u.t[2] = f2bf(a.z); u.t[3] = f2bf(a.w);
    u.t[4] = f2bf(b.x); u.t[5] = f2bf(b.y); u.t[6] = f2bf(b.z); u.t[7] = f2bf(b.w);
    *(int4*)(Xb + base + h * 8) = u.v;
  }
}

// ---------------- main GEMM: 256^2 tile, 8-phase, counted vmcnt ----------------
// LDS XOR-swizzle (proven conflict-free in previous kernel): 16B granule g of
// local row r stored at g ^ (r&7); achieved by pre-swizzling the GLOBAL source
// granule, LDS dest stays linear (global_load_lds requirement).
// A-frag: A[m=lane&15][k=(lane>>4)*8+j]; C/D: col=lane&15, row=(lane>>4)*4+reg.
//
// Per K-tile (4 phases, two s_barrier each):
//  ph0: ds_read af[0..3][ks] + bfv[0..1][ks] (12 reads) | BAR | MFMA Q(m0,n0) | BAR
//  ph1: ds_read af[4..7][ks] + bfv[2..3][ks] (12 reads) | BAR | MFMA Q(m0,n1) | BAR
//  ph2: stage A(t+2) into this slot (reads of slot done ph1) | BAR | Q(m1,n0) | BAR
//  ph3: stage B(t+2); vmcnt(8)  <- leaves t+2's 8 loads in flight, guarantees
//       t+1 fully landed for ALL waves before the barrier | BAR | Q(m1,n1) | BAR

__global__ __launch_bounds__(512, 2) void gemm_pre512(const u16* __restrict__ A,
                                                      const u16* __restrict__ B,
                                                      const float* __restrict__ bias,
                                                      float* __restrict__ C) {
  __shared__ __align__(16) u16 As[2][BM * BK];   // 2 x 32 KB
  __shared__ __align__(16) u16 Bs[2][BN * BK];   // 2 x 32 KB  (total 128 KB)
  const int tid = threadIdx.x;
  const int lane = tid & 63;
  const int wid = __builtin_amdgcn_readfirstlane(tid >> 6);

  // XCD-aware bijective block swizzle (NWG % 8 == 0), bn-fastest within chunk
  const int lin = blockIdx.x;
  const int wg = (lin & 7) * (NWG / 8) + (lin >> 3);
  const int bm = wg / GX;
  const int bn = wg % GX;

  const u16* Ab = A + (size_t)bm * BM * INF;
  const u16* Bb = B + (size_t)bn * BN * INF;

  // staging addressing: one global_load_lds covers 64 rows (8 rows/wave)
  const int rowoff = tid >> 3;                    // 0..63
  const int gran = (tid & 7) ^ (rowoff & 7);      // pre-swizzled source granule
  const u16* Asrc = Ab + (size_t)rowoff * INF + gran * 8;
  const u16* Bsrc = Bb + (size_t)rowoff * INF + gran * 8;
  const int wid8 = wid * 8;

  // frag addressing
  const int rr = lane & 15;
  const int q4 = lane >> 4;
  const int wm = wid >> 2;   // 0..1 -> 128-row half of A tile
  const int wn = wid & 3;    // 0..3 -> 64-row quarter of B tile

  f32x4 acc[8][4] = {};
  bf16x8 af[8][2], bfv[4][2];

#define STAGE_A(S, TT)                                                         \
  _Pragma("unroll") for (int r0 = 0; r0 < BM; r0 += 64)                        \
    async_copy16(Asrc + (size_t)r0 * INF + (TT) * BK,                          \
                 (const char*)&As[S][0] + (r0 + wid8) * 128);
#define STAGE_B(S, TT)                                                         \
  _Pragma("unroll") for (int r0 = 0; r0 < BN; r0 += 64)                        \
    async_copy16(Bsrc + (size_t)r0 * INF + (TT) * BK,                          \
                 (const char*)&Bs[S][0] + (r0 + wid8) * 128);

#define LD_A(S, MH)                                                            \
  _Pragma("unroll") for (int mi = 0; mi < 4; ++mi)                             \
    _Pragma("unroll") for (int ks = 0; ks < 2; ++ks)                           \
      af[(MH) * 4 + mi][ks] = *(const bf16x8*)&As[S][                          \
          (wm * 128 + ((MH) * 4 + mi) * 16 + rr) * BK +                        \
          (((ks * 4 + q4) ^ (rr & 7)) * 8)];
#define LD_B(S, NH)                                                            \
  _Pragma("unroll") for (int ni = 0; ni < 2; ++ni)                             \
    _Pragma("unroll") for (int ks = 0; ks < 2; ++ks)                           \
      bfv[(NH) * 2 + ni][ks] = *(const bf16x8*)&Bs[S][                         \
          (wn * 64 + ((NH) * 2 + ni) * 16 + rr) * BK +                         \
          (((ks * 4 + q4) ^ (rr & 7)) * 8)];

#define MFMAQ(MH, NH)                                                          \
  do {                                                                         \
    __builtin_amdgcn_s_setprio(1);                                             \
    _Pragma("unroll") for (int ks = 0; ks < 2; ++ks)                           \
      _Pragma("unroll") for (int mi = 0; mi < 4; ++mi)                         \
        _Pragma("unroll") for (int ni = 0; ni < 2; ++ni)                       \
          acc[(MH) * 4 + mi][(NH) * 2 + ni] =                                  \
              __builtin_amdgcn_mfma_f32_16x16x32_bf16(                         \
                  af[(MH) * 4 + mi][ks], bfv[(NH) * 2 + ni][ks],               \
                  acc[(MH) * 4 + mi][(NH) * 2 + ni], 0, 0, 0);                 \
    __builtin_amdgcn_s_setprio(0);                                             \
  } while (0)

#define TILE(S, T)                                                             \
  do {                                                                         \
    LD_A(S, 0); LD_B(S, 0);                                                    \
    BAR(); MFMAQ(0, 0); BAR();                                                 \
    LD_A(S, 1); LD_B(S, 1);                                                    \
    BAR(); MFMAQ(0, 1); BAR();                                                 \
    if ((T) < NT - 2) { STAGE_A(S, (T) + 2); }                                 \
    BAR(); MFMAQ(1, 0); BAR();                                                 \
    if ((T) < NT - 2) { STAGE_B(S, (T) + 2); VMCNT(8); } else { VMCNT(0); }    \
    BAR(); MFMAQ(1, 1); BAR();                                                 \
  } while (0)

  // prologue: tile 0 -> slot 0, tile 1 -> slot 1; wait tile 0 (oldest 8 of 16)
  STAGE_A(0, 0); STAGE_B(0, 0);
  STAGE_A(1, 1); STAGE_B(1, 1);
  VMCNT(8);
  BAR();

  for (int t = 0; t < NT; t += 2) {
    TILE(0, t);
    TILE(1, t + 1);
  }

  // epilogue
  const int ncol = lane & 15;
  const int qrow = (lane >> 4) * 4;
  float bv[4];
#pragma unroll
  for (int ni = 0; ni < 4; ++ni)
    bv[ni] = bias[bn * BN + wn * 64 + ni * 16 + ncol];
#pragma unroll
  for (int mi = 0; mi < 8; ++mi)
#pragma unroll
    for (int ni = 0; ni < 4; ++ni) {
      const int gn = bn * BN + wn * 64 + ni * 16 + ncol;
#pragma unroll
      for (int r = 0; r < 4; ++r) {
        const int gm = bm * BM + wm * 128 + mi * 16 + qrow + r;
        C[(size_t)gm * OUTF + gn] = acc[mi][ni][r] + bv[ni];
      }
    }
}

// ---------------- fused fallback (no workspace requirement) ----------------
// old 128x128 / 256-thread structure, self-contained

#define FBM 128
#define FBN 128

#define FMFMA_COMPUTE()                                                       \
  do {                                                                        \
    const int frr = lane & 15;                                                \
    const int fq4 = lane >> 4;                                                \
    _Pragma("unroll") for (int ks = 0; ks < 2; ++ks) {                        \
      bf16x8 fa[4], fb[4];                                                    \
      const int kk = (((ks * 4 + fq4) ^ (frr & 7)) * 8);                      \
      _Pragma("unroll") for (int i = 0; i < 4; ++i) {                         \
        fa[i] = *(const bf16x8*)&Asf[(mwave + i * 16 + frr) * BK + kk];       \
        fb[i] = *(const bf16x8*)&Bsf[(nwave + i * 16 + frr) * BK + kk];       \
      }                                                                       \
      _Pragma("unroll") for (int mi = 0; mi < 4; ++mi)                        \
        _Pragma("unroll") for (int ni = 0; ni < 4; ++ni)                      \
          facc[mi][ni] = __builtin_amdgcn_mfma_f32_16x16x32_bf16(             \
              fa[mi], fb[ni], facc[mi][ni], 0, 0, 0);                         \
    }                                                                         \
  } while (0)

__global__ __launch_bounds__(256) void gemm_fused(const float* __restrict__ X,
                                                  const int* __restrict__ QW,
                                                  const float* __restrict__ scales,
                                                  const float* __restrict__ zeros,
                                                  const float* __restrict__ bias,
                                                  float* __restrict__ C) {
  __shared__ __align__(16) u16 Asf[FBM * BK];
  __shared__ __align__(16) u16 Bsf[FBN * BK];
  const int tid = threadIdx.x;
  const int lane = tid & 63;
  const int wid = tid >> 6;
  const int bm = blockIdx.y, bn = blockIdx.x;
  const int row = tid >> 1;
  const int half = tid & 1;
  const float* xr = X + (size_t)(bm * FBM + row) * INF + half * 32;
  const int* qr = QW + (size_t)(bn * FBN + row) * KB4 + half * 16;
  const float* srow = scales + (size_t)(bn * FBN + row) * NG;
  const float* zrow = zeros + (size_t)(bn * FBN + row) * NG;
  const int mwave = (wid >> 1) * 64;
  const int nwave = (wid & 1) * 64;
  f32x4 facc[4][4] = {};

  for (int kb = 0; kb < INF / BK; ++kb) {
    const int k0 = kb * BK;
    union { u16 t[32]; int4 v[4]; } ta, tb;
#pragma unroll
    for (int j = 0; j < 8; ++j) {
      const float4 f = *(const float4*)(xr + k0 + j * 4);
      ta.t[4 * j]     = f2bf(f.x);
      ta.t[4 * j + 1] = f2bf(f.y);
      ta.t[4 * j + 2] = f2bf(f.z);
      ta.t[4 * j + 3] = f2bf(f.w);
    }
    {
      const float s = srow[kb >> 1];
      const float zs = -zrow[kb >> 1] * s;
#pragma unroll
      for (int j = 0; j < 4; ++j) {
        const int4 q = *(const int4*)(qr + kb * 32 + j * 4);
        const int qq[4] = {q.x, q.y, q.z, q.w};
#pragma unroll
        for (int u = 0; u < 4; ++u) {
          tb.t[8 * j + 2 * u]     = f2bf(fmaf((float)(qq[u] & 15), s, zs));
          tb.t[8 * j + 2 * u + 1] = f2bf(fmaf((float)((qq[u] >> 4) & 15), s, zs));
        }
      }
    }
    __syncthreads();
#pragma unroll
    for (int j = 0; j < 4; ++j) {
      *(int4*)&Asf[row * BK + (((half * 4 + j) ^ (row & 7)) * 8)] = ta.v[j];
      *(int4*)&Bsf[row * BK + (((half * 4 + j) ^ (row & 7)) * 8)] = tb.v[j];
    }
    __syncthreads();
    FMFMA_COMPUTE();
  }
  {
    const int ncol = lane & 15;
    const int qrow = (lane >> 4) * 4;
#pragma unroll
    for (int mi = 0; mi < 4; ++mi)
#pragma unroll
      for (int ni = 0; ni < 4; ++ni) {
        const int gn = bn * FBN + nwave + ni * 16 + ncol;
        const float bvv = bias[gn];
#pragma unroll
        for (int r = 0; r < 4; ++r) {
          const int gm = bm * FBM + mwave + mi * 16 + qrow + r;
          C[(size_t)gm * OUTF + gn] = facc[mi][ni][r] + bvv;
        }
      }
  }
}

// ---------------- launch ----------------

extern "C" void kernel_launch(void* const* d_in, const int* in_sizes, int n_in,
                              void* d_out, int out_size, void* d_ws, size_t ws_size,
                              hipStream_t stream) {
  const float* x = (const float*)d_in[0];
  const int* qw = (const int*)d_in[1];
  const float* scales = (const float*)d_in[2];
  const float* zeros = (const float*)d_in[3];
  const float* bias = (const float*)d_in[4];
  float* out = (float*)d_out;

  const size_t needW = (size_t)OUTF * INF * sizeof(u16);  // 90,177,536 B
  const size_t needX = (size_t)TOK * INF * sizeof(u16);   // 67,108,864 B

  if (ws_size >= needW + needX) {
    u16* Wb = (u16*)d_ws;
    u16* Xb = (u16*)((char*)d_ws + needW);
    dequant_w<<<(OUTF * KB4 / 8) / 256, 256, 0, stream>>>(qw, scales, zeros, Wb);
    cvt_x<<<(TOK * INF / 16) / 256, 256, 0, stream>>>(x, Xb);
    gemm_pre512<<<dim3(NWG), 512, 0, stream>>>(Xb, Wb, bias, out);
  } else {
    gemm_fused<<<dim3(OUTF / FBN, TOK / FBM), 256, 0, stream>>>(x, qw, scales, zeros, bias, out);
  }
}